// Round 4
// baseline (137.520 us; speedup 1.0000x reference)
//
#include <hip/hip_runtime.h>
#include <hip/hip_bf16.h>

#define N_ITEMS 8192
#define DIM 64
#define BATCH 4096
#define NCLASS 50
#define JS 8                           // j-splits per i-tile
#define WPB 4                          // waves per block
#define JR (N_ITEMS / (JS * WPB))      // 256 j-rows per wave
#define NTILES (JR / 32)               // 8 tiles of 32 j-rows
#define ITILES (N_ITEMS / 64)          // 128 i-tiles
#define GRAM_BLOCKS (ITILES * JS)      // 1024 MFMA blocks
#define TOTAL_BLOCKS (GRAM_BLOCKS + NCLASS)
#define INV_T (1.0f / 0.07f)
#define LOG2E 1.4426950408889634f

typedef __bf16 bf16_t;
typedef __attribute__((ext_vector_type(8))) __bf16 bf16x8;
typedef __attribute__((ext_vector_type(16))) float f32x16;

#if __has_builtin(__builtin_amdgcn_exp2f)
#define EXP2(x) __builtin_amdgcn_exp2f(x)
#else
#define EXP2(x) __expf((x) * 0.6931471805599453f)
#endif

__device__ __forceinline__ float wave_sum(float v) {
    #pragma unroll
    for (int off = 32; off; off >>= 1) v += __shfl_xor(v, off, 64);
    return v;
}

// Prep: normalize rows -> bf16 featB, zero S/Lc/scnt + loss slot; rating head.
// Blocks [0,2048): normalize, 4 rows each. Blocks [2048,3072): rating.
__global__ __launch_bounds__(256) void prep_rating(
    const float* __restrict__ emb, const int* __restrict__ idx,
    const float* __restrict__ aw, const float* __restrict__ ab,
    bf16_t* __restrict__ featB, float* __restrict__ S,
    float* __restrict__ Lc, int* __restrict__ scnt,
    float* __restrict__ out) {
    int t = threadIdx.x, lane = t & 63, w = t >> 6;
    int bid = blockIdx.x;
    if (bid < N_ITEMS / 4) {
        int row = bid * 4 + w;
        float x = emb[row * DIM + lane];
        float ss = wave_sum(x * x);
        float f = x * __frsqrt_rn(fmaxf(ss, 1e-24f));
        featB[row * DIM + lane] = (bf16_t)f;
        if (lane == 0) S[row] = 0.f;
        if (bid == 0) {
            if (t < NCLASS) Lc[t] = 0.f;
            if (t <= ITILES) scnt[t] = 0;       // 128 i-tile counters + done
            if (t == 0) out[BATCH] = 0.f;
        }
    } else {
        int row = (bid - N_ITEMS / 4) * 4 + w;
        int it = idx[row];
        float x = emb[it * DIM + lane] * aw[lane];
        x = wave_sum(x);
        if (lane == 0) out[row] = 1.0f / (1.0f + __expf(-(x + ab[0])));
    }
}

// Blocks [0,50): class gather (dispatched FIRST so the latency-bound scan
//   overlaps the MFMA blocks instead of trailing them). Writes T1/wgt with
//   agent-scope release stores (coherent point, no stale dirty L2 lines).
// Blocks [50,1074): MFMA Gram + fused exp-sum into S. The 8th block to
//   finish an i-tile (scnt acq_rel counter) computes log(S_i+eps) for its
//   64 rows and scatters into Lc[class]. The last of all 1074 blocks
//   (done counter) folds sum_c (wgt_c*Lc_c - T1_c) into out_loss.
__global__ __launch_bounds__(256) void gram_gather(
    const bf16_t* __restrict__ featB, const int* __restrict__ labels,
    float* __restrict__ S, float* __restrict__ T1, float* __restrict__ wgt,
    float* __restrict__ Lc, int* __restrict__ scnt,
    float* __restrict__ out_loss) {
    __shared__ float sh[4][64];
    __shared__ float sc4[4];
    __shared__ int sflag;
    __shared__ int cflag;
    int b = blockIdx.x;
    int t = threadIdx.x, lane = t & 63, wv = t >> 6;

    if (b < NCLASS) {
        int c = b;
        float gacc = 0.f, cacc = 0.f;
        for (int strip = wv; strip < N_ITEMS / 64; strip += 4) {
            int r = strip * 64 + lane;
            bool match = (labels[r] == c);
            unsigned long long mask = __ballot(match);
            cacc += match ? 1.f : 0.f;
            const bf16_t* base = featB + (size_t)strip * 64 * DIM + lane;
            while (mask) {
                int bit = __builtin_ctzll(mask);
                mask &= mask - 1;
                gacc += (float)base[bit * DIM];   // 128B coalesced row load
            }
        }
        cacc = wave_sum(cacc);
        sh[wv][lane] = gacc;
        if (lane == 0) sc4[wv] = cacc;
        __syncthreads();
        if (wv == 0) {
            float g = (sh[0][lane] + sh[1][lane]) + (sh[2][lane] + sh[3][lane]);
            float dot = wave_sum(g * g);
            if (lane == 0) {
                float cnt = (sc4[0] + sc4[1]) + (sc4[2] + sc4[3]);
                float C = cnt - 1.f;
                bool ok = (C > 0.5f);
                float t1v = ok ? (dot - (1.f + C) * cnt) * INV_T / (C + 1e-6f) : 0.f;
                float wv_ = ok ? C / (C + 1e-6f) : 0.f;
                __hip_atomic_store(&T1[c], t1v, __ATOMIC_RELEASE,
                                   __HIP_MEMORY_SCOPE_AGENT);
                __hip_atomic_store(&wgt[c], wv_, __ATOMIC_RELEASE,
                                   __HIP_MEMORY_SCOPE_AGENT);
                __threadfence();
            }
        }
    } else {
        const float scale = INV_T * LOG2E;
        const float bias = -INV_T * LOG2E;
        int bb = b - NCLASS;
        int itile = bb >> 3;
        int col = lane & 31, half = lane >> 5;
        int i0 = itile * 64;
        int ig0 = i0 + col, ig1 = i0 + 32 + col;

        // B frags for the two i-groups (identical addressing to A — Gram)
        bf16x8 bf0[4], bf1[4];
        const bf16_t* b0p = featB + (size_t)ig0 * DIM + half * 8;
        const bf16_t* b1p = featB + (size_t)ig1 * DIM + half * 8;
        #pragma unroll
        for (int s = 0; s < 4; ++s) {
            bf0[s] = *reinterpret_cast<const bf16x8*>(b0p + s * 16);
            bf1[s] = *reinterpret_cast<const bf16x8*>(b1p + s * 16);
        }

        int jbase = ((bb & 7) * WPB + wv) * JR;
        int rowoff = half * 4;
        float p0[4] = {0.f, 0.f, 0.f, 0.f}, p1[4] = {0.f, 0.f, 0.f, 0.f};

        for (int tile = 0; tile < NTILES; ++tile) {
            int jt = jbase + tile * 32;
            const bf16_t* arowp = featB + (size_t)(jt + col) * DIM + half * 8;
            f32x16 c0 = {}, c1 = {};
            #pragma unroll
            for (int s = 0; s < 4; ++s) {
                bf16x8 a = *reinterpret_cast<const bf16x8*>(arowp + s * 16);
                c0 = __builtin_amdgcn_mfma_f32_32x32x16_bf16(a, bf0[s], c0, 0, 0, 0);
                c1 = __builtin_amdgcn_mfma_f32_32x32x16_bf16(a, bf1[s], c1, 0, 0, 0);
            }
            if (jt != i0) {
                #pragma unroll
                for (int r = 0; r < 16; ++r)
                    p0[r & 3] += EXP2(fmaf(c0[r], scale, bias));
            } else {
                #pragma unroll
                for (int r = 0; r < 16; ++r) {
                    int jrow = (r & 3) + 8 * (r >> 2) + rowoff;
                    float e = EXP2(fmaf(c0[r], scale, bias));
                    p0[r & 3] += (jrow != col) ? e : 0.f;
                }
            }
            if (jt != i0 + 32) {
                #pragma unroll
                for (int r = 0; r < 16; ++r)
                    p1[r & 3] += EXP2(fmaf(c1[r], scale, bias));
            } else {
                #pragma unroll
                for (int r = 0; r < 16; ++r) {
                    int jrow = (r & 3) + 8 * (r >> 2) + rowoff;
                    float e = EXP2(fmaf(c1[r], scale, bias));
                    p1[r & 3] += (jrow != col) ? e : 0.f;
                }
            }
        }
        float a0 = (p0[0] + p0[1]) + (p0[2] + p0[3]);
        float a1 = (p1[0] + p1[1]) + (p1[2] + p1[3]);
        a0 += __shfl_xor(a0, 32, 64);   // full i-tile0 sum, all lanes
        a1 += __shfl_xor(a1, 32, 64);
        sh[wv][lane] = (lane < 32) ? a0 : a1;
        __syncthreads();
        if (wv == 0) {
            float s = (sh[0][lane] + sh[1][lane]) + (sh[2][lane] + sh[3][lane]);
            unsafeAtomicAdd(&S[i0 + lane], s);
            __threadfence();
            if (lane == 0) {
                int old = __hip_atomic_fetch_add(&scnt[itile], 1,
                                                 __ATOMIC_ACQ_REL,
                                                 __HIP_MEMORY_SCOPE_AGENT);
                sflag = (old == JS - 1);
            }
        }
        __syncthreads();
        if (sflag && wv == 0) {
            // All 8 j-split contributions for this i-tile are in S (acq_rel
            // counter ordered). Finalize the 64 rows: log + class scatter.
            float sv = __hip_atomic_load(&S[i0 + lane], __ATOMIC_RELAXED,
                                         __HIP_MEMORY_SCOPE_AGENT);
            float lv = __logf(sv + 1e-6f);
            unsafeAtomicAdd(&Lc[labels[i0 + lane]], lv);
            __threadfence();
        }
    }

    // Common tail: global done counter; last block combines the loss.
    if (t == 0) {
        int old = __hip_atomic_fetch_add(&scnt[ITILES], 1, __ATOMIC_ACQ_REL,
                                         __HIP_MEMORY_SCOPE_AGENT);
        cflag = (old == TOTAL_BLOCKS - 1);
    }
    __syncthreads();
    if (cflag && wv == 0) {
        float v = 0.f;
        if (lane < NCLASS) {
            float t1 = __hip_atomic_load(&T1[lane], __ATOMIC_RELAXED,
                                         __HIP_MEMORY_SCOPE_AGENT);
            float w  = __hip_atomic_load(&wgt[lane], __ATOMIC_RELAXED,
                                         __HIP_MEMORY_SCOPE_AGENT);
            float lc = __hip_atomic_load(&Lc[lane], __ATOMIC_RELAXED,
                                         __HIP_MEMORY_SCOPE_AGENT);
            v = w * lc - t1;
        }
        v = wave_sum(v);
        if (lane == 0) out_loss[0] = v * (1.0f / (float)N_ITEMS);
    }
}

extern "C" void kernel_launch(void* const* d_in, const int* in_sizes, int n_in,
                              void* d_out, int out_size, void* d_ws, size_t ws_size,
                              hipStream_t stream) {
    const int*   item_indices = (const int*)d_in[0];
    const int*   labels       = (const int*)d_in[1];
    const float* emb          = (const float*)d_in[2];
    const float* aw           = (const float*)d_in[3];
    const float* ab           = (const float*)d_in[4];
    float* out = (float*)d_out;   // [4096 ratings][1 supcon]

    bf16_t* featB = (bf16_t*)d_ws;                       // 8192*64 bf16 (1 MB)
    float*  S     = (float*)(featB + N_ITEMS * DIM);     // 8192
    float*  T1    = S + N_ITEMS;                         // 50
    float*  wgt   = T1 + NCLASS;                         // 50
    float*  Lc    = wgt + NCLASS;                        // 50 per-class log-sums
    int*    scnt  = (int*)(Lc + NCLASS);                 // 128 i-tile ctrs + done

    prep_rating<<<N_ITEMS / 4 + BATCH / 4, 256, 0, stream>>>(
        emb, item_indices, aw, ab, featB, S, Lc, scnt, out);

    gram_gather<<<TOTAL_BLOCKS, 256, 0, stream>>>(
        featB, labels, S, T1, wgt, Lc, scnt, out + BATCH);
}

// Round 7
// 95.058 us; speedup vs baseline: 1.4467x; 1.4467x over previous
//
#include <hip/hip_runtime.h>
#include <hip/hip_bf16.h>

#define N_ITEMS 8192
#define DIM 64
#define BATCH 4096
#define NCLASS 50
#define JS 8                           // j-splits
#define WPB 4                          // waves per block
#define JR (N_ITEMS / (JS * WPB))      // 256 j-rows per wave
#define NTILES (JR / 32)               // 8 tiles of 32 j-rows
#define GRAM_BLOCKS (128 * JS)         // 1024 MFMA blocks; +NCLASS gather blocks
#define INV_T (1.0f / 0.07f)
#define LOG2E 1.4426950408889634f

typedef __bf16 bf16_t;
typedef __attribute__((ext_vector_type(8))) __bf16 bf16x8;
typedef __attribute__((ext_vector_type(16))) float f32x16;

#if __has_builtin(__builtin_amdgcn_exp2f)
#define EXP2(x) __builtin_amdgcn_exp2f(x)
#else
#define EXP2(x) __expf((x) * 0.6931471805599453f)
#endif

__device__ __forceinline__ float wave_sum(float v) {
    #pragma unroll
    for (int off = 32; off; off >>= 1) v += __shfl_xor(v, off, 64);
    return v;
}

// Prep: normalize rows -> bf16 featB, zero S + loss slot; rating head. No atomics.
// Blocks [0,2048): normalize, 4 rows each. Blocks [2048,3072): rating.
__global__ __launch_bounds__(256) void prep_rating(
    const float* __restrict__ emb, const int* __restrict__ idx,
    const float* __restrict__ aw, const float* __restrict__ ab,
    bf16_t* __restrict__ featB, float* __restrict__ S,
    float* __restrict__ out) {
    int t = threadIdx.x, lane = t & 63, w = t >> 6;
    int bid = blockIdx.x;
    if (bid < N_ITEMS / 4) {
        int row = bid * 4 + w;
        float x = emb[row * DIM + lane];
        float ss = wave_sum(x * x);
        float f = x * __frsqrt_rn(fmaxf(ss, 1e-24f));
        featB[row * DIM + lane] = (bf16_t)f;
        if (lane == 0) S[row] = 0.f;
        if (bid == 0 && t == 0) out[BATCH] = 0.f;
    } else {
        int row = (bid - N_ITEMS / 4) * 4 + w;
        int it = idx[row];
        float x = emb[it * DIM + lane] * aw[lane];
        x = wave_sum(x);
        if (lane == 0) out[row] = 1.0f / (1.0f + __expf(-(x + ab[0])));
    }
}

// Blocks [0,50): class gather for c = b (dispatched FIRST so the latency-bound
//   scan overlaps the MFMA blocks instead of trailing them; featB-only):
//   g_c = sum_{i in c} feat_i, cnt_c; writes
//   T1[c] = (|g_c|^2 - (1+C)*cnt)*INV_T/(C+1e-6), wgt[c] = C/(C+1e-6) (0 if C<1).
// Blocks [50,1074): MFMA Gram + fused exp-sum into S (m_i == 1/T analytically),
//   LDS-reduced across the block's 4 waves -> 64 atomics/block.
__global__ __launch_bounds__(256) void gram_gather(
    const bf16_t* __restrict__ featB, const int* __restrict__ labels,
    float* __restrict__ S, float* __restrict__ T1, float* __restrict__ wgt) {
    __shared__ float sh[4][64];
    __shared__ float sc4[4];
    int b = blockIdx.x;
    int t = threadIdx.x, lane = t & 63, wv = t >> 6;

    if (b < NCLASS) {
        int c = b;
        float gacc = 0.f, cacc = 0.f;
        for (int strip = wv; strip < N_ITEMS / 64; strip += 4) {
            int r = strip * 64 + lane;
            bool match = (labels[r] == c);
            unsigned long long mask = __ballot(match);
            cacc += match ? 1.f : 0.f;
            const bf16_t* base = featB + (size_t)strip * 64 * DIM + lane;
            while (mask) {
                int bit = __builtin_ctzll(mask);
                mask &= mask - 1;
                gacc += (float)base[bit * DIM];   // 128B coalesced row load
            }
        }
        cacc = wave_sum(cacc);
        sh[wv][lane] = gacc;
        if (lane == 0) sc4[wv] = cacc;
        __syncthreads();
        if (wv == 0) {
            float g = (sh[0][lane] + sh[1][lane]) + (sh[2][lane] + sh[3][lane]);
            float dot = wave_sum(g * g);
            if (lane == 0) {
                float cnt = (sc4[0] + sc4[1]) + (sc4[2] + sc4[3]);
                float C = cnt - 1.f;
                bool ok = (C > 0.5f);
                T1[c]  = ok ? (dot - (1.f + C) * cnt) * INV_T / (C + 1e-6f) : 0.f;
                wgt[c] = ok ? C / (C + 1e-6f) : 0.f;
            }
        }
    } else {
        const float scale = INV_T * LOG2E;
        const float bias = -INV_T * LOG2E;
        int bb = b - NCLASS;
        int col = lane & 31, half = lane >> 5;
        int i0 = (bb >> 3) * 64;
        int ig0 = i0 + col, ig1 = i0 + 32 + col;

        // B frags for the two i-groups (identical addressing to A — Gram matrix)
        bf16x8 bf0[4], bf1[4];
        const bf16_t* b0p = featB + (size_t)ig0 * DIM + half * 8;
        const bf16_t* b1p = featB + (size_t)ig1 * DIM + half * 8;
        #pragma unroll
        for (int s = 0; s < 4; ++s) {
            bf0[s] = *reinterpret_cast<const bf16x8*>(b0p + s * 16);
            bf1[s] = *reinterpret_cast<const bf16x8*>(b1p + s * 16);
        }

        int jbase = ((bb & 7) * WPB + wv) * JR;
        int rowoff = half * 4;
        float p0[4] = {0.f, 0.f, 0.f, 0.f}, p1[4] = {0.f, 0.f, 0.f, 0.f};

        for (int tile = 0; tile < NTILES; ++tile) {
            int jt = jbase + tile * 32;
            const bf16_t* arowp = featB + (size_t)(jt + col) * DIM + half * 8;
            f32x16 c0 = {}, c1 = {};
            #pragma unroll
            for (int s = 0; s < 4; ++s) {
                bf16x8 a = *reinterpret_cast<const bf16x8*>(arowp + s * 16);
                c0 = __builtin_amdgcn_mfma_f32_32x32x16_bf16(a, bf0[s], c0, 0, 0, 0);
                c1 = __builtin_amdgcn_mfma_f32_32x32x16_bf16(a, bf1[s], c1, 0, 0, 0);
            }
            if (jt != i0) {
                #pragma unroll
                for (int r = 0; r < 16; ++r)
                    p0[r & 3] += EXP2(fmaf(c0[r], scale, bias));
            } else {
                #pragma unroll
                for (int r = 0; r < 16; ++r) {
                    int jrow = (r & 3) + 8 * (r >> 2) + rowoff;
                    float e = EXP2(fmaf(c0[r], scale, bias));
                    p0[r & 3] += (jrow != col) ? e : 0.f;
                }
            }
            if (jt != i0 + 32) {
                #pragma unroll
                for (int r = 0; r < 16; ++r)
                    p1[r & 3] += EXP2(fmaf(c1[r], scale, bias));
            } else {
                #pragma unroll
                for (int r = 0; r < 16; ++r) {
                    int jrow = (r & 3) + 8 * (r >> 2) + rowoff;
                    float e = EXP2(fmaf(c1[r], scale, bias));
                    p1[r & 3] += (jrow != col) ? e : 0.f;
                }
            }
        }
        float a0 = (p0[0] + p0[1]) + (p0[2] + p0[3]);
        float a1 = (p1[0] + p1[1]) + (p1[2] + p1[3]);
        a0 += __shfl_xor(a0, 32, 64);   // full i-tile0 sum, all lanes
        a1 += __shfl_xor(a1, 32, 64);
        // rs[wv][lane] is this wave's contribution to S[i0+lane]
        sh[wv][lane] = (lane < 32) ? a0 : a1;
        __syncthreads();
        if (wv == 0) {
            float s = (sh[0][lane] + sh[1][lane]) + (sh[2][lane] + sh[3][lane]);
            unsafeAtomicAdd(&S[i0 + lane], s);
        }
    }
}

// loss = (1/N) * [ sum_i wgt[l_i]*log(S_i+1e-6)  -  sum_c T1_c ]
// 32 blocks x 256, one row per thread; block 0 wave 0 folds in -sum(T1).
__global__ __launch_bounds__(256) void finalize_k(
    const float* __restrict__ S, const int* __restrict__ labels,
    const float* __restrict__ T1, const float* __restrict__ wgt,
    float* __restrict__ out_loss) {
    __shared__ float red[4];
    int t = threadIdx.x, lane = t & 63, wv = t >> 6;
    int r = blockIdx.x * 256 + t;
    float acc = wgt[labels[r]] * __logf(S[r] + 1e-6f);
    float v = wave_sum(acc);
    float t1s = 0.f;
    if (blockIdx.x == 0 && wv == 0) {
        float t1v = (lane < NCLASS) ? T1[lane] : 0.f;
        t1s = wave_sum(t1v);
    }
    if (lane == 0) red[wv] = v;
    __syncthreads();
    if (t == 0) {
        float s = (red[0] + red[1]) + (red[2] + red[3]);
        s -= t1s;   // nonzero only in block 0
        unsafeAtomicAdd(out_loss, s / (float)N_ITEMS);
    }
}

extern "C" void kernel_launch(void* const* d_in, const int* in_sizes, int n_in,
                              void* d_out, int out_size, void* d_ws, size_t ws_size,
                              hipStream_t stream) {
    const int*   item_indices = (const int*)d_in[0];
    const int*   labels       = (const int*)d_in[1];
    const float* emb          = (const float*)d_in[2];
    const float* aw           = (const float*)d_in[3];
    const float* ab           = (const float*)d_in[4];
    float* out = (float*)d_out;   // [4096 ratings][1 supcon]

    bf16_t* featB = (bf16_t*)d_ws;                       // 8192*64 bf16 (1 MB)
    float*  S     = (float*)(featB + N_ITEMS * DIM);     // 8192
    float*  T1    = S + N_ITEMS;                         // 50
    float*  wgt   = T1 + NCLASS;                         // 50

    prep_rating<<<N_ITEMS / 4 + BATCH / 4, 256, 0, stream>>>(
        emb, item_indices, aw, ab, featB, S, out);

    gram_gather<<<GRAM_BLOCKS + NCLASS, 256, 0, stream>>>(
        featB, labels, S, T1, wgt);

    finalize_k<<<N_ITEMS / 256, 256, 0, stream>>>(S, labels, T1, wgt,
                                                  out + BATCH);
}